// Round 26
// baseline (3900.363 us; speedup 1.0000x reference)
//
#include <hip/hip_runtime.h>

namespace {

constexpr int Bc   = 4;
constexpr int Nc   = 4096;
constexpr int Kc   = 20;
constexpr int BNc  = Bc * Nc;        // 16384
constexpr int PIXc = BNc * Kc;       // 327680
constexpr float  NEGINF = -3.0e38f;
constexpr double EPSD   = (double)1e-5f;

// ================================================================ xx = jnp.sum(x*x, -1), XLA reduce
template<int C>
__global__ __launch_bounds__(256)
void compute_xx_xla(const float* __restrict__ X, float* __restrict__ xxf) {
    int i = blockIdx.x * 256 + threadIdx.x;
    if (i >= BNc) return;
    const float* xp = X + (size_t)i * C;
    if constexpr (C == 3) {
        const float q0 = __fmul_rn(xp[0], xp[0]);
        const float q1 = __fmul_rn(xp[1], xp[1]);
        const float q2 = __fmul_rn(xp[2], xp[2]);
        xxf[i] = __fadd_rn(__fadd_rn(q0, q1), q2);
    } else {
        float acc[16];
#pragma unroll
        for (int l = 0; l < 16; ++l) acc[l] = 0.f;
#pragma unroll
        for (int blk = 0; blk < 4; ++blk)
#pragma unroll
            for (int l = 0; l < 16; ++l)
                acc[l] = __fadd_rn(acc[l], __fmul_rn(xp[blk * 16 + l], xp[blk * 16 + l]));
        float a8[8];
#pragma unroll
        for (int l = 0; l < 8; ++l) a8[l] = __fadd_rn(acc[l], acc[l + 8]);
        float a4[4];
#pragma unroll
        for (int l = 0; l < 4; ++l) a4[l] = __fadd_rn(a8[l], a8[l + 4]);
        xxf[i] = __fadd_rn(__fadd_rn(a4[0], a4[2]), __fadd_rn(a4[1], a4[3]));
    }
}

// ================================================================ fused pair + top-20 select
// One block per (b, row-tile of 64). Streams 64 column-tiles: stage panel ->
// pair_tile's bit-identical score chains -> Sb in LDS -> per-(row,chunk)
// streaming register top-20 (strict > admit, evict latest-indexed min = exact
// chunk-local lex top-k) -> final per-row lex merge (tie -> lowest index).
// Output identical to pair_tile + brute_select; S never materialized.
template<int C>
__global__ __launch_bounds__(256)
void knn_fused(const float* __restrict__ X, const float* __restrict__ xxf,
               int* __restrict__ knnIdx) {
    constexpr int P = C + 1;
    constexpr int CMPF = 2 * 64 * P + 64 * 65 + 128;       // compute-phase floats
    constexpr int MRGB = 64 * 80 * 8;                      // merge-phase bytes
    constexpr int SMEMB = (CMPF * 4 > MRGB) ? CMPF * 4 : MRGB;
    __shared__ alignas(16) char smem_raw[SMEMB];
    float* sxn   = (float*)smem_raw;                        // [64][P]
    float* sxm   = sxn + 64 * P;                            // [64][P]
    float* Sb    = sxm + 64 * P;                            // [64][65]
    float* sxxn  = Sb + 64 * 65;
    float* sxxm  = sxxn + 64;
    float* candV = (float*)smem_raw;                        // merge phase alias
    int*   candI = (int*)(candV + 64 * 80);

    const int tid = threadIdx.x;
    const int b   = blockIdx.x >> 6;
    const int tn  = blockIdx.x & 63;

    const float* Xn = X + ((size_t)b * Nc + tn * 64) * C;
    for (int f = tid; f < 64 * C; f += 256) {
        const int row = f / C, c = f - row * C;
        sxn[row * P + c] = Xn[f];
    }
    if (tid < 64) sxxn[tid] = xxf[b * Nc + tn * 64 + tid];

    // per-thread streaming top-20 over its (row, chunk): m % 4 == selc
    float vals[Kc]; int idxs[Kc];
#pragma unroll
    for (int j = 0; j < Kc; ++j) { vals[j] = NEGINF; idxs[j] = -1; }
    float mv = NEGINF;
    const int selr = tid & 63, selc = tid >> 6;

    const int ty = tid >> 4, tx = tid & 15;
    const int rn0 = ty * 4, rm0 = tx * 4;

    for (int tm = 0; tm < 64; ++tm) {
        __syncthreads();                                    // prev selection done
        const float* Xm = X + ((size_t)b * Nc + tm * 64) * C;
        for (int f = tid; f < 64 * C; f += 256) {
            const int row = f / C, c = f - row * C;
            sxm[row * P + c] = Xm[f];
        }
        if (tid < 64) sxxm[tid] = xxf[b * Nc + tm * 64 + tid];
        __syncthreads();

        float a[4][4];
#pragma unroll
        for (int i = 0; i < 4; ++i)
#pragma unroll
            for (int j = 0; j < 4; ++j) a[i][j] = 0.f;
#pragma unroll 4
        for (int c = 0; c < C; ++c) {
            float nv[4], mvv[4];
#pragma unroll
            for (int i = 0; i < 4; ++i) nv[i]  = sxn[(rn0 + i) * P + c];
#pragma unroll
            for (int j = 0; j < 4; ++j) mvv[j] = sxm[(rm0 + j) * P + c];
#pragma unroll
            for (int i = 0; i < 4; ++i)
#pragma unroll
                for (int j = 0; j < 4; ++j)
                    a[i][j] = __builtin_fmaf(nv[i], mvv[j], a[i][j]);
        }
#pragma unroll
        for (int i = 0; i < 4; ++i) {
            const float xn_ = sxxn[rn0 + i];
#pragma unroll
            for (int j = 0; j < 4; ++j)
                Sb[(rn0 + i) * 65 + rm0 + j] =
                    __fsub_rn(__fsub_rn(__fmul_rn(2.0f, a[i][j]), xn_), sxxm[rm0 + j]);
        }
        __syncthreads();

        const float* Srow = &Sb[selr * 65];
        const int mbase = tm * 64;
#pragma unroll
        for (int i = 0; i < 16; ++i) {
            const int mloc = i * 4 + selc;
            const float val = Srow[mloc];
            if (val > mv) {                                 // streaming insert
                const int m = mbase + mloc;
                int slot = 0; int worst = -2;
#pragma unroll
                for (int j = 0; j < Kc; ++j) {
                    const bool cnd = (vals[j] == mv) && (idxs[j] > worst);
                    worst = cnd ? idxs[j] : worst;
                    slot  = cnd ? j : slot;
                }
#pragma unroll
                for (int j = 0; j < Kc; ++j) {
                    vals[j] = (j == slot) ? val : vals[j];
                    idxs[j] = (j == slot) ? m   : idxs[j];
                }
                float nm = 3.0e38f;
#pragma unroll
                for (int j = 0; j < Kc; ++j) nm = fminf(nm, vals[j]);
                mv = nm;
            }
        }
    }
    __syncthreads();                                        // last selection done
#pragma unroll
    for (int s = 0; s < Kc; ++s) {
        candV[selr * 80 + selc * Kc + s] = vals[s];
        candI[selr * 80 + selc * Kc + s] = idxs[s];
    }
    __syncthreads();
    if (tid < 64) {
        const int r = tid;
        int* outp = knnIdx + ((size_t)b * Nc + tn * 64 + r) * Kc;
        for (int round = 0; round < Kc; ++round) {
            float bv = NEGINF; int bi = 0x7fffffff; int bq = 0;
            for (int q = 0; q < 80; ++q) {
                const float v = candV[r * 80 + q];
                const int   ii = candI[r * 80 + q];
                const bool better = (v > bv) || (v == bv && ii < bi);
                bv = better ? v : bv;
                bi = better ? ii : bi;
                bq = better ? q : bq;
            }
            outp[round] = bi;
            candV[r * 80 + bq] = NEGINF;
        }
    }
}

// ---------------------------------------------------------------- BN+lrelu apply (fp32 chain)
__device__ __forceinline__ float bn_lrelu_np(float hv, float m, float r,
                                             float g, float bb) {
    float t = __fsub_rn(hv, m);
    t = __fmul_rn(g, t);
    t = __fmul_rn(t, r);
    t = __fadd_rn(t, bb);
    return t >= 0.f ? t : __fmul_rn(0.2f, t);
}

// ================================================================ edge conv CIN=3 + fused stats
__global__ __launch_bounds__(256)
void edge_conv3(const float* __restrict__ X, const int* __restrict__ knn,
                const float* __restrict__ W, float* __restrict__ h,
                double* __restrict__ stats) {
    constexpr int F = 6, PW = 8, TP = 64;
    __shared__ float sA[TP * PW];
    __shared__ float sWT[F * 65];
    __shared__ double sp[4 * 128];
    const int tid = threadIdx.x;
    for (int f = tid; f < 64 * F; f += 256) {
        const int o = f / F, cc = f - o * F;
        sWT[cc * 65 + o] = W[f];
    }
    const int pix0 = blockIdx.x * TP;
    for (int f = tid; f < TP * F; f += 256) {
        const int pix = f / F, c = f - pix * F;
        const int p  = pix0 + pix;
        const int bn = p / Kc;
        const int b  = bn >> 12;
        const int j  = knn[p];
        float v;
        if (c < 3) v = __fsub_rn(X[((size_t)(b << 12) + j) * 3 + c],
                                 X[(size_t)bn * 3 + c]);
        else       v = X[(size_t)bn * 3 + (c - 3)];
        sA[pix * PW + c] = v;
    }
    __syncthreads();
    const int ty = tid >> 4, tx = tid & 15;
    const int p0 = ty * 4, o0 = tx * 4;
    float acc[4][4];
#pragma unroll
    for (int i = 0; i < 4; ++i)
#pragma unroll
        for (int j = 0; j < 4; ++j) acc[i][j] = 0.f;
#pragma unroll
    for (int c = 0; c < F; ++c) {
        float av[4], wv[4];
#pragma unroll
        for (int i = 0; i < 4; ++i) av[i] = sA[(p0 + i) * PW + c];
#pragma unroll
        for (int j = 0; j < 4; ++j) wv[j] = sWT[c * 65 + o0 + j];
#pragma unroll
        for (int i = 0; i < 4; ++i)
#pragma unroll
            for (int j = 0; j < 4; ++j)
                acc[i][j] = __builtin_fmaf(av[i], wv[j], acc[i][j]);
    }
#pragma unroll
    for (int i = 0; i < 4; ++i)
        *(float4*)&h[(size_t)(pix0 + p0 + i) * 64 + o0] =
            make_float4(acc[i][0], acc[i][1], acc[i][2], acc[i][3]);
    double s1[4], s2[4];
#pragma unroll
    for (int j = 0; j < 4; ++j) { s1[j] = 0.0; s2[j] = 0.0; }
#pragma unroll
    for (int i = 0; i < 4; ++i)
#pragma unroll
        for (int j = 0; j < 4; ++j) {
            const double d = (double)acc[i][j];
            s1[j] += d; s2[j] += d * d;
        }
#pragma unroll
    for (int mask = 16; mask <= 32; mask <<= 1)
#pragma unroll
        for (int j = 0; j < 4; ++j) {
            s1[j] += __shfl_xor(s1[j], mask);
            s2[j] += __shfl_xor(s2[j], mask);
        }
    if ((tid & 48) == 0) {
        const int w = tid >> 6;
#pragma unroll
        for (int j = 0; j < 4; ++j) {
            sp[w * 128 + o0 + j]      = s1[j];
            sp[w * 128 + 64 + o0 + j] = s2[j];
        }
    }
    __syncthreads();
    if (tid < 128)
        atomicAdd(&stats[tid], sp[tid] + sp[128 + tid] + sp[256 + tid] + sp[384 + tid]);
}

// ================================================================ edge conv CIN=64 (r24 config): TP=64, split-K, 2p x 8o
__global__ __launch_bounds__(256)
void edge_conv64(const float* __restrict__ X, const int* __restrict__ knn,
                 const float* __restrict__ W, float* __restrict__ h,
                 double* __restrict__ stats) {
    __shared__ alignas(16) float smem[64 * 129 + 64 * 68];
    float*  sA  = smem;                               // [64 pix][129]
    float*  sWT = smem + 64 * 129;                    // [64 cc][68]
    double* sp  = (double*)smem;                      // aliases sA after compute
    const int tid = threadIdx.x;
    const int pix0 = blockIdx.x * 64;
    for (int f = tid; f < 8192; f += 256) {
        const int pix = f >> 7, c = f & 127;
        const int p  = pix0 + pix;
        const int bn = p / Kc;
        const int b  = bn >> 12;
        const int j  = knn[p];
        float v;
        if (c < 64) v = __fsub_rn(X[((size_t)(b << 12) + j) * 64 + c],
                                  X[(size_t)bn * 64 + c]);
        else        v = X[(size_t)bn * 64 + (c - 64)];
        sA[pix * 129 + c] = v;
    }
    const int og = tid & 7, pg = tid >> 3;
    const int p0 = pg * 2, o0 = og * 8;
    float acc[2][8];
#pragma unroll
    for (int i = 0; i < 2; ++i)
#pragma unroll
        for (int j = 0; j < 8; ++j) acc[i][j] = 0.f;
#pragma unroll
    for (int ph = 0; ph < 2; ++ph) {
        for (int f = tid; f < 4096; f += 256) {
            const int o = f >> 6, cc = f & 63;
            sWT[cc * 68 + o] = W[o * 128 + ph * 64 + cc];
        }
        __syncthreads();
#pragma unroll 2
        for (int cc = 0; cc < 64; ++cc) {
            const int c = ph * 64 + cc;
            const float4 w0 = *(const float4*)&sWT[cc * 68 + o0];
            const float4 w1 = *(const float4*)&sWT[cc * 68 + o0 + 4];
            const float a0 = sA[(p0    ) * 129 + c];
            const float a1 = sA[(p0 + 1) * 129 + c];
            acc[0][0] = __builtin_fmaf(a0, w0.x, acc[0][0]); acc[0][1] = __builtin_fmaf(a0, w0.y, acc[0][1]);
            acc[0][2] = __builtin_fmaf(a0, w0.z, acc[0][2]); acc[0][3] = __builtin_fmaf(a0, w0.w, acc[0][3]);
            acc[0][4] = __builtin_fmaf(a0, w1.x, acc[0][4]); acc[0][5] = __builtin_fmaf(a0, w1.y, acc[0][5]);
            acc[0][6] = __builtin_fmaf(a0, w1.z, acc[0][6]); acc[0][7] = __builtin_fmaf(a0, w1.w, acc[0][7]);
            acc[1][0] = __builtin_fmaf(a1, w0.x, acc[1][0]); acc[1][1] = __builtin_fmaf(a1, w0.y, acc[1][1]);
            acc[1][2] = __builtin_fmaf(a1, w0.z, acc[1][2]); acc[1][3] = __builtin_fmaf(a1, w0.w, acc[1][3]);
            acc[1][4] = __builtin_fmaf(a1, w1.x, acc[1][4]); acc[1][5] = __builtin_fmaf(a1, w1.y, acc[1][5]);
            acc[1][6] = __builtin_fmaf(a1, w1.z, acc[1][6]); acc[1][7] = __builtin_fmaf(a1, w1.w, acc[1][7]);
        }
        __syncthreads();
    }
#pragma unroll
    for (int i = 0; i < 2; ++i) {
        float* dst = &h[(size_t)(pix0 + p0 + i) * 64 + o0];
        *(float4*)dst       = make_float4(acc[i][0], acc[i][1], acc[i][2], acc[i][3]);
        *(float4*)(dst + 4) = make_float4(acc[i][4], acc[i][5], acc[i][6], acc[i][7]);
    }
    double s1[8], s2[8];
#pragma unroll
    for (int j = 0; j < 8; ++j) { s1[j] = 0.0; s2[j] = 0.0; }
#pragma unroll
    for (int i = 0; i < 2; ++i)
#pragma unroll
        for (int j = 0; j < 8; ++j) {
            const double d = (double)acc[i][j];
            s1[j] += d; s2[j] += d * d;
        }
#pragma unroll
    for (int mask = 8; mask <= 32; mask <<= 1)
#pragma unroll
        for (int j = 0; j < 8; ++j) {
            s1[j] += __shfl_xor(s1[j], mask);
            s2[j] += __shfl_xor(s2[j], mask);
        }
    __syncthreads();
    if ((tid & 56) == 0) {
        const int w = tid >> 6;
#pragma unroll
        for (int j = 0; j < 8; ++j) {
            sp[w * 128 + o0 + j]      = s1[j];
            sp[w * 128 + 64 + o0 + j] = s2[j];
        }
    }
    __syncthreads();
    if (tid < 128)
        atomicAdd(&stats[tid], sp[tid] + sp[128 + tid] + sp[256 + tid] + sp[384 + tid]);
}

// ================================================================ hidden conv (r24 config): TP=128, 4p x 8o
__global__ __launch_bounds__(256)
void hidden_conv_tile(float* __restrict__ h, const float* __restrict__ W,
                      const float* __restrict__ mr, const float* __restrict__ g,
                      const float* __restrict__ bt, double* __restrict__ stats) {
    __shared__ alignas(16) float smem[128 * 65 + 64 * 68];
    float*  sA  = smem;                               // [128 pix][65]
    float*  sWT = smem + 128 * 65;                    // [64 c][68]
    double* sp  = (double*)smem;                      // aliases sA after compute
    const int tid = threadIdx.x;
    for (int f = tid; f < 4096; f += 256) {
        const int o = f >> 6, c = f & 63;
        sWT[c * 68 + o] = W[f];
    }
    const size_t pix0 = (size_t)blockIdx.x * 128;
    for (int f = tid; f < 8192; f += 256) {
        const int pix = f >> 6, c = f & 63;
        const float hv = h[(pix0 + pix) * 64 + c];
        sA[pix * 65 + c] = bn_lrelu_np(hv, mr[c], mr[64 + c], g[c], bt[c]);
    }
    __syncthreads();

    const int og = tid & 7, pg = tid >> 3;
    const int p0 = pg * 4, o0 = og * 8;
    float acc[4][8];
#pragma unroll
    for (int i = 0; i < 4; ++i)
#pragma unroll
        for (int j = 0; j < 8; ++j) acc[i][j] = 0.f;
#pragma unroll 2
    for (int c = 0; c < 64; ++c) {
        const float4 w0 = *(const float4*)&sWT[c * 68 + o0];
        const float4 w1 = *(const float4*)&sWT[c * 68 + o0 + 4];
        float av[4];
#pragma unroll
        for (int i = 0; i < 4; ++i) av[i] = sA[(p0 + i) * 65 + c];
#pragma unroll
        for (int i = 0; i < 4; ++i) {
            acc[i][0] = __builtin_fmaf(av[i], w0.x, acc[i][0]);
            acc[i][1] = __builtin_fmaf(av[i], w0.y, acc[i][1]);
            acc[i][2] = __builtin_fmaf(av[i], w0.z, acc[i][2]);
            acc[i][3] = __builtin_fmaf(av[i], w0.w, acc[i][3]);
            acc[i][4] = __builtin_fmaf(av[i], w1.x, acc[i][4]);
            acc[i][5] = __builtin_fmaf(av[i], w1.y, acc[i][5]);
            acc[i][6] = __builtin_fmaf(av[i], w1.z, acc[i][6]);
            acc[i][7] = __builtin_fmaf(av[i], w1.w, acc[i][7]);
        }
    }
#pragma unroll
    for (int i = 0; i < 4; ++i) {
        float* dst = &h[(pix0 + p0 + i) * 64 + o0];
        *(float4*)dst       = make_float4(acc[i][0], acc[i][1], acc[i][2], acc[i][3]);
        *(float4*)(dst + 4) = make_float4(acc[i][4], acc[i][5], acc[i][6], acc[i][7]);
    }
    double s1[8], s2[8];
#pragma unroll
    for (int j = 0; j < 8; ++j) { s1[j] = 0.0; s2[j] = 0.0; }
#pragma unroll
    for (int i = 0; i < 4; ++i)
#pragma unroll
        for (int j = 0; j < 8; ++j) {
            const double d = (double)acc[i][j];
            s1[j] += d; s2[j] += d * d;
        }
#pragma unroll
    for (int mask = 8; mask <= 32; mask <<= 1)
#pragma unroll
        for (int j = 0; j < 8; ++j) {
            s1[j] += __shfl_xor(s1[j], mask);
            s2[j] += __shfl_xor(s2[j], mask);
        }
    __syncthreads();
    if ((tid & 56) == 0) {
        const int w = tid >> 6;
#pragma unroll
        for (int j = 0; j < 8; ++j) {
            sp[w * 128 + o0 + j]      = s1[j];
            sp[w * 128 + 64 + o0 + j] = s2[j];
        }
    }
    __syncthreads();
    if (tid < 128)
        atomicAdd(&stats[tid], sp[tid] + sp[128 + tid] + sp[256 + tid] + sp[384 + tid]);
}

// ---------------------------------------------------------------- max over k (BN apply)
__global__ __launch_bounds__(256)
void maxk_np(const float* __restrict__ h, const float* __restrict__ mr,
             const float* __restrict__ g, const float* __restrict__ bt,
             float* __restrict__ out) {
    const int i  = blockIdx.x * 256 + threadIdx.x;
    const int o  = i & 63;
    const int bn = i >> 6;
    const float m = mr[o], r = mr[64 + o], gg = g[o], bb = bt[o];
    const float* hp = h + (size_t)bn * Kc * 64 + o;
    float mx = NEGINF;
#pragma unroll
    for (int k = 0; k < Kc; ++k) mx = fmaxf(mx, bn_lrelu_np(hp[k * 64], m, r, gg, bb));
    out[i] = mx;
}

// ---------------------------------------------------------------- finalize (fp64 stats -> fp32 m,r)
__global__ void finalize_f(const double* __restrict__ stats, float* __restrict__ mr) {
    const int o = threadIdx.x;
    const double inv  = 1.0 / (double)PIXc;
    const double mean = stats[o] * inv;
    const double var  = stats[64 + o] * inv - mean * mean;
    mr[o]      = (float)mean;
    mr[64 + o] = (float)(1.0 / sqrt(var + EPSD));
}

} // namespace

extern "C" void kernel_launch(void* const* d_in, const int* in_sizes, int n_in,
                              void* d_out, int out_size, void* d_ws, size_t ws_size,
                              hipStream_t stream) {
    (void)in_sizes; (void)n_in; (void)out_size; (void)ws_size;
    const float* x     = (const float*)d_in[0];
    const float* w[9]  = {(const float*)d_in[1], (const float*)d_in[2], (const float*)d_in[3],
                          (const float*)d_in[4], (const float*)d_in[5], (const float*)d_in[6],
                          (const float*)d_in[7], (const float*)d_in[8], (const float*)d_in[9]};
    const float* gamma = (const float*)d_in[10];
    const float* beta  = (const float*)d_in[11];
    float* out = (float*)d_out;

    double* statsD = (double*)d_ws;                   // 9*128 doubles
    float*  mr     = (float*)(statsD + 9 * 128);      // 9*128 floats
    float*  xxf    = mr + 9 * 128;                    // BN
    int*  knnIdx   = (int*)(xxf + BNc);               // PIX ints
    float* x1      = (float*)(knnIdx + PIXc);         // BN*64
    float* x2      = x1 + (size_t)BNc * 64;           // BN*64
    float* h       = x2 + (size_t)BNc * 64;           // PIX*64 f = 83.9 MB

    hipMemsetAsync(statsD, 0, 9 * 128 * sizeof(double), stream);

    // ---- stage 1 (C=3)
    compute_xx_xla<3><<<64, 256, 0, stream>>>(x, xxf);
    knn_fused<3><<<256, 256, 0, stream>>>(x, xxf, knnIdx);
    edge_conv3<<<PIXc / 64, 256, 0, stream>>>(x, knnIdx, w[0], h, statsD + 0 * 128);
    finalize_f<<<1, 64, 0, stream>>>(statsD + 0 * 128, mr + 0 * 128);
    hidden_conv_tile<<<PIXc / 128, 256, 0, stream>>>(h, w[1], mr + 0 * 128, gamma + 0 * 64, beta + 0 * 64, statsD + 1 * 128);
    finalize_f<<<1, 64, 0, stream>>>(statsD + 1 * 128, mr + 1 * 128);
    hidden_conv_tile<<<PIXc / 128, 256, 0, stream>>>(h, w[2], mr + 1 * 128, gamma + 1 * 64, beta + 1 * 64, statsD + 2 * 128);
    finalize_f<<<1, 64, 0, stream>>>(statsD + 2 * 128, mr + 2 * 128);
    maxk_np<<<4096, 256, 0, stream>>>(h, mr + 2 * 128, gamma + 2 * 64, beta + 2 * 64, x1);

    // ---- stage 2 (C=64)
    compute_xx_xla<64><<<64, 256, 0, stream>>>(x1, xxf);
    knn_fused<64><<<256, 256, 0, stream>>>(x1, xxf, knnIdx);
    edge_conv64<<<PIXc / 64, 256, 0, stream>>>(x1, knnIdx, w[3], h, statsD + 3 * 128);
    finalize_f<<<1, 64, 0, stream>>>(statsD + 3 * 128, mr + 3 * 128);
    hidden_conv_tile<<<PIXc / 128, 256, 0, stream>>>(h, w[4], mr + 3 * 128, gamma + 3 * 64, beta + 3 * 64, statsD + 4 * 128);
    finalize_f<<<1, 64, 0, stream>>>(statsD + 4 * 128, mr + 4 * 128);
    hidden_conv_tile<<<PIXc / 128, 256, 0, stream>>>(h, w[5], mr + 4 * 128, gamma + 4 * 64, beta + 4 * 64, statsD + 5 * 128);
    finalize_f<<<1, 64, 0, stream>>>(statsD + 5 * 128, mr + 5 * 128);
    maxk_np<<<4096, 256, 0, stream>>>(h, mr + 5 * 128, gamma + 5 * 64, beta + 5 * 64, x2);

    // ---- stage 3 (C=64)
    compute_xx_xla<64><<<64, 256, 0, stream>>>(x2, xxf);
    knn_fused<64><<<256, 256, 0, stream>>>(x2, xxf, knnIdx);
    edge_conv64<<<PIXc / 64, 256, 0, stream>>>(x2, knnIdx, w[6], h, statsD + 6 * 128);
    finalize_f<<<1, 64, 0, stream>>>(statsD + 6 * 128, mr + 6 * 128);
    hidden_conv_tile<<<PIXc / 128, 256, 0, stream>>>(h, w[7], mr + 6 * 128, gamma + 6 * 64, beta + 6 * 64, statsD + 7 * 128);
    finalize_f<<<1, 64, 0, stream>>>(statsD + 7 * 128, mr + 7 * 128);
    hidden_conv_tile<<<PIXc / 128, 256, 0, stream>>>(h, w[8], mr + 7 * 128, gamma + 7 * 64, beta + 7 * 64, statsD + 8 * 128);
    finalize_f<<<1, 64, 0, stream>>>(statsD + 8 * 128, mr + 8 * 128);
    maxk_np<<<4096, 256, 0, stream>>>(h, mr + 8 * 128, gamma + 8 * 64, beta + 8 * 64, out);
}

// Round 27
// 3426.017 us; speedup vs baseline: 1.1385x; 1.1385x over previous
//
#include <hip/hip_runtime.h>

namespace {

constexpr int Bc   = 4;
constexpr int Nc   = 4096;
constexpr int Kc   = 20;
constexpr int BNc  = Bc * Nc;        // 16384
constexpr int PIXc = BNc * Kc;       // 327680
constexpr float  NEGINF = -3.0e38f;
constexpr double EPSD   = (double)1e-5f;

// ================================================================ xx = jnp.sum(x*x, -1), XLA reduce
template<int C>
__global__ __launch_bounds__(256)
void compute_xx_xla(const float* __restrict__ X, float* __restrict__ xxf) {
    int i = blockIdx.x * 256 + threadIdx.x;
    if (i >= BNc) return;
    const float* xp = X + (size_t)i * C;
    if constexpr (C == 3) {
        const float q0 = __fmul_rn(xp[0], xp[0]);
        const float q1 = __fmul_rn(xp[1], xp[1]);
        const float q2 = __fmul_rn(xp[2], xp[2]);
        xxf[i] = __fadd_rn(__fadd_rn(q0, q1), q2);
    } else {
        float acc[16];
#pragma unroll
        for (int l = 0; l < 16; ++l) acc[l] = 0.f;
#pragma unroll
        for (int blk = 0; blk < 4; ++blk)
#pragma unroll
            for (int l = 0; l < 16; ++l)
                acc[l] = __fadd_rn(acc[l], __fmul_rn(xp[blk * 16 + l], xp[blk * 16 + l]));
        float a8[8];
#pragma unroll
        for (int l = 0; l < 8; ++l) a8[l] = __fadd_rn(acc[l], acc[l + 8]);
        float a4[4];
#pragma unroll
        for (int l = 0; l < 4; ++l) a4[l] = __fadd_rn(a8[l], a8[l + 4]);
        xxf[i] = __fadd_rn(__fadd_rn(a4[0], a4[2]), __fadd_rn(a4[1], a4[3]));
    }
}

// ================================================================ pair, LDS-tiled (bit-identical math)
template<int C>
__global__ __launch_bounds__(256)
void pair_tile(const float* __restrict__ X, const float* __restrict__ xxf,
               float* __restrict__ S, int b) {
    constexpr int P = C + 1;
    __shared__ float sxn[64 * P], sxm[64 * P];
    __shared__ float sxxn[64], sxxm[64];
    const int tid = threadIdx.x;
    const int tn  = blockIdx.x >> 6;
    const int tm  = blockIdx.x & 63;
    const float* Xn = X + ((size_t)b * Nc + tn * 64) * C;
    const float* Xm = X + ((size_t)b * Nc + tm * 64) * C;
    for (int f = tid; f < 64 * C; f += 256) {
        const int row = f / C, c = f - row * C;
        sxn[row * P + c] = Xn[f];
        sxm[row * P + c] = Xm[f];
    }
    if (tid < 64)        sxxn[tid]      = xxf[b * Nc + tn * 64 + tid];
    else if (tid < 128)  sxxm[tid - 64] = xxf[b * Nc + tm * 64 + (tid - 64)];
    __syncthreads();

    const int rn0 = (tid >> 4) * 4;
    const int rm0 = (tid & 15) * 4;
    float a00=0,a01=0,a02=0,a03=0, a10=0,a11=0,a12=0,a13=0;
    float a20=0,a21=0,a22=0,a23=0, a30=0,a31=0,a32=0,a33=0;
#pragma unroll 4
    for (int c = 0; c < C; ++c) {
        const float n0 = sxn[(rn0    ) * P + c];
        const float n1 = sxn[(rn0 + 1) * P + c];
        const float n2 = sxn[(rn0 + 2) * P + c];
        const float n3 = sxn[(rn0 + 3) * P + c];
        const float m0 = sxm[(rm0    ) * P + c];
        const float m1 = sxm[(rm0 + 1) * P + c];
        const float m2 = sxm[(rm0 + 2) * P + c];
        const float m3 = sxm[(rm0 + 3) * P + c];
        a00 = __builtin_fmaf(n0, m0, a00); a01 = __builtin_fmaf(n0, m1, a01);
        a02 = __builtin_fmaf(n0, m2, a02); a03 = __builtin_fmaf(n0, m3, a03);
        a10 = __builtin_fmaf(n1, m0, a10); a11 = __builtin_fmaf(n1, m1, a11);
        a12 = __builtin_fmaf(n1, m2, a12); a13 = __builtin_fmaf(n1, m3, a13);
        a20 = __builtin_fmaf(n2, m0, a20); a21 = __builtin_fmaf(n2, m1, a21);
        a22 = __builtin_fmaf(n2, m2, a22); a23 = __builtin_fmaf(n2, m3, a23);
        a30 = __builtin_fmaf(n3, m0, a30); a31 = __builtin_fmaf(n3, m1, a31);
        a32 = __builtin_fmaf(n3, m2, a32); a33 = __builtin_fmaf(n3, m3, a33);
    }
    const float xm0 = sxxm[rm0], xm1 = sxxm[rm0 + 1], xm2 = sxxm[rm0 + 2], xm3 = sxxm[rm0 + 3];
#define PAIR_ROW(i, r0, r1, r2, r3)                                                     \
    {                                                                                   \
        const float xn_ = sxxn[rn0 + i];                                                \
        float4 v;                                                                       \
        v.x = __fsub_rn(__fsub_rn(__fmul_rn(2.0f, r0), xn_), xm0);                      \
        v.y = __fsub_rn(__fsub_rn(__fmul_rn(2.0f, r1), xn_), xm1);                      \
        v.z = __fsub_rn(__fsub_rn(__fmul_rn(2.0f, r2), xn_), xm2);                      \
        v.w = __fsub_rn(__fsub_rn(__fmul_rn(2.0f, r3), xn_), xm3);                      \
        *(float4*)&S[(size_t)(tn * 64 + rn0 + i) * Nc + tm * 64 + rm0] = v;             \
    }
    PAIR_ROW(0, a00, a01, a02, a03)
    PAIR_ROW(1, a10, a11, a12, a13)
    PAIR_ROW(2, a20, a21, a22, a23)
    PAIR_ROW(3, a30, a31, a32, a33)
#undef PAIR_ROW
}

// ---------------------------------------------------------------- top-20 select (tie -> lowest index)
__global__ __launch_bounds__(256)
void brute_select(const float* __restrict__ S, int* __restrict__ knnIdx, int b) {
    const int lane = threadIdx.x & 63;
    const int wv   = threadIdx.x >> 6;
    const int n    = blockIdx.x * 4 + wv;
    const float* Sr = S + (size_t)n * Nc;
    float v[64];
#pragma unroll
    for (int j = 0; j < 64; ++j) v[j] = Sr[j * 64 + lane];
    int* outp = knnIdx + ((size_t)b * Nc + n) * Kc;
    for (int round = 0; round < Kc; ++round) {
        float bv = NEGINF; int bi = 0x7fffffff;
#pragma unroll
        for (int j = 0; j < 64; ++j) {
            const int mi = j * 64 + lane;
            const bool better = (v[j] > bv) || (v[j] == bv && mi < bi);
            bv = better ? v[j] : bv;
            bi = better ? mi : bi;
        }
#pragma unroll
        for (int s = 1; s < 64; s <<= 1) {
            const float ov = __shfl_xor(bv, s);
            const int   oi = __shfl_xor(bi, s);
            const bool better = (ov > bv) || (ov == bv && oi < bi);
            bv = better ? ov : bv;
            bi = better ? oi : bi;
        }
        if (lane == 0) outp[round] = bi;
#pragma unroll
        for (int j = 0; j < 64; ++j)
            if (j == (bi >> 6) && (bi & 63) == lane) v[j] = NEGINF;
    }
}

// ---------------------------------------------------------------- BN+lrelu apply (fp32 chain)
__device__ __forceinline__ float bn_lrelu_np(float hv, float m, float r,
                                             float g, float bb) {
    float t = __fsub_rn(hv, m);
    t = __fmul_rn(g, t);
    t = __fmul_rn(t, r);
    t = __fadd_rn(t, bb);
    return t >= 0.f ? t : __fmul_rn(0.2f, t);
}

// ================================================================ edge conv CIN=3 + fused stats
__global__ __launch_bounds__(256)
void edge_conv3(const float* __restrict__ X, const int* __restrict__ knn,
                const float* __restrict__ W, float* __restrict__ h,
                double* __restrict__ stats) {
    constexpr int F = 6, PW = 8, TP = 64;
    __shared__ float sA[TP * PW];
    __shared__ float sWT[F * 65];
    __shared__ double sp[4 * 128];
    const int tid = threadIdx.x;
    for (int f = tid; f < 64 * F; f += 256) {
        const int o = f / F, cc = f - o * F;
        sWT[cc * 65 + o] = W[f];
    }
    const int pix0 = blockIdx.x * TP;
    for (int f = tid; f < TP * F; f += 256) {
        const int pix = f / F, c = f - pix * F;
        const int p  = pix0 + pix;
        const int bn = p / Kc;
        const int b  = bn >> 12;
        const int j  = knn[p];
        float v;
        if (c < 3) v = __fsub_rn(X[((size_t)(b << 12) + j) * 3 + c],
                                 X[(size_t)bn * 3 + c]);
        else       v = X[(size_t)bn * 3 + (c - 3)];
        sA[pix * PW + c] = v;
    }
    __syncthreads();
    const int ty = tid >> 4, tx = tid & 15;
    const int p0 = ty * 4, o0 = tx * 4;
    float acc[4][4];
#pragma unroll
    for (int i = 0; i < 4; ++i)
#pragma unroll
        for (int j = 0; j < 4; ++j) acc[i][j] = 0.f;
#pragma unroll
    for (int c = 0; c < F; ++c) {
        float av[4], wv[4];
#pragma unroll
        for (int i = 0; i < 4; ++i) av[i] = sA[(p0 + i) * PW + c];
#pragma unroll
        for (int j = 0; j < 4; ++j) wv[j] = sWT[c * 65 + o0 + j];
#pragma unroll
        for (int i = 0; i < 4; ++i)
#pragma unroll
            for (int j = 0; j < 4; ++j)
                acc[i][j] = __builtin_fmaf(av[i], wv[j], acc[i][j]);
    }
#pragma unroll
    for (int i = 0; i < 4; ++i)
        *(float4*)&h[(size_t)(pix0 + p0 + i) * 64 + o0] =
            make_float4(acc[i][0], acc[i][1], acc[i][2], acc[i][3]);
    double s1[4], s2[4];
#pragma unroll
    for (int j = 0; j < 4; ++j) { s1[j] = 0.0; s2[j] = 0.0; }
#pragma unroll
    for (int i = 0; i < 4; ++i)
#pragma unroll
        for (int j = 0; j < 4; ++j) {
            const double d = (double)acc[i][j];
            s1[j] += d; s2[j] += d * d;
        }
#pragma unroll
    for (int mask = 16; mask <= 32; mask <<= 1)
#pragma unroll
        for (int j = 0; j < 4; ++j) {
            s1[j] += __shfl_xor(s1[j], mask);
            s2[j] += __shfl_xor(s2[j], mask);
        }
    if ((tid & 48) == 0) {
        const int w = tid >> 6;
#pragma unroll
        for (int j = 0; j < 4; ++j) {
            sp[w * 128 + o0 + j]      = s1[j];
            sp[w * 128 + 64 + o0 + j] = s2[j];
        }
    }
    __syncthreads();
    if (tid < 128)
        atomicAdd(&stats[tid], sp[tid] + sp[128 + tid] + sp[256 + tid] + sp[384 + tid]);
}

// ================================================================ edge conv CIN=64: TP=64, split-K, 2p x 8o + fused stats
__global__ __launch_bounds__(256)
void edge_conv64(const float* __restrict__ X, const int* __restrict__ knn,
                 const float* __restrict__ W, float* __restrict__ h,
                 double* __restrict__ stats) {
    __shared__ alignas(16) float smem[64 * 129 + 64 * 68];
    float*  sA  = smem;                               // [64 pix][129]
    float*  sWT = smem + 64 * 129;                    // [64 cc][68]
    double* sp  = (double*)smem;                      // aliases sA after compute
    const int tid = threadIdx.x;
    const int pix0 = blockIdx.x * 64;
    for (int f = tid; f < 8192; f += 256) {
        const int pix = f >> 7, c = f & 127;
        const int p  = pix0 + pix;
        const int bn = p / Kc;
        const int b  = bn >> 12;
        const int j  = knn[p];
        float v;
        if (c < 64) v = __fsub_rn(X[((size_t)(b << 12) + j) * 64 + c],
                                  X[(size_t)bn * 64 + c]);
        else        v = X[(size_t)bn * 64 + (c - 64)];
        sA[pix * 129 + c] = v;
    }
    const int og = tid & 7, pg = tid >> 3;
    const int p0 = pg * 2, o0 = og * 8;
    float acc[2][8];
#pragma unroll
    for (int i = 0; i < 2; ++i)
#pragma unroll
        for (int j = 0; j < 8; ++j) acc[i][j] = 0.f;
#pragma unroll
    for (int ph = 0; ph < 2; ++ph) {
        for (int f = tid; f < 4096; f += 256) {
            const int o = f >> 6, cc = f & 63;
            sWT[cc * 68 + o] = W[o * 128 + ph * 64 + cc];
        }
        __syncthreads();
#pragma unroll 2
        for (int cc = 0; cc < 64; ++cc) {
            const int c = ph * 64 + cc;
            const float4 w0 = *(const float4*)&sWT[cc * 68 + o0];
            const float4 w1 = *(const float4*)&sWT[cc * 68 + o0 + 4];
            const float a0 = sA[(p0    ) * 129 + c];
            const float a1 = sA[(p0 + 1) * 129 + c];
            acc[0][0] = __builtin_fmaf(a0, w0.x, acc[0][0]); acc[0][1] = __builtin_fmaf(a0, w0.y, acc[0][1]);
            acc[0][2] = __builtin_fmaf(a0, w0.z, acc[0][2]); acc[0][3] = __builtin_fmaf(a0, w0.w, acc[0][3]);
            acc[0][4] = __builtin_fmaf(a0, w1.x, acc[0][4]); acc[0][5] = __builtin_fmaf(a0, w1.y, acc[0][5]);
            acc[0][6] = __builtin_fmaf(a0, w1.z, acc[0][6]); acc[0][7] = __builtin_fmaf(a0, w1.w, acc[0][7]);
            acc[1][0] = __builtin_fmaf(a1, w0.x, acc[1][0]); acc[1][1] = __builtin_fmaf(a1, w0.y, acc[1][1]);
            acc[1][2] = __builtin_fmaf(a1, w0.z, acc[1][2]); acc[1][3] = __builtin_fmaf(a1, w0.w, acc[1][3]);
            acc[1][4] = __builtin_fmaf(a1, w1.x, acc[1][4]); acc[1][5] = __builtin_fmaf(a1, w1.y, acc[1][5]);
            acc[1][6] = __builtin_fmaf(a1, w1.z, acc[1][6]); acc[1][7] = __builtin_fmaf(a1, w1.w, acc[1][7]);
        }
        __syncthreads();
    }
#pragma unroll
    for (int i = 0; i < 2; ++i) {
        float* dst = &h[(size_t)(pix0 + p0 + i) * 64 + o0];
        *(float4*)dst       = make_float4(acc[i][0], acc[i][1], acc[i][2], acc[i][3]);
        *(float4*)(dst + 4) = make_float4(acc[i][4], acc[i][5], acc[i][6], acc[i][7]);
    }
    double s1[8], s2[8];
#pragma unroll
    for (int j = 0; j < 8; ++j) { s1[j] = 0.0; s2[j] = 0.0; }
#pragma unroll
    for (int i = 0; i < 2; ++i)
#pragma unroll
        for (int j = 0; j < 8; ++j) {
            const double d = (double)acc[i][j];
            s1[j] += d; s2[j] += d * d;
        }
#pragma unroll
    for (int mask = 8; mask <= 32; mask <<= 1)
#pragma unroll
        for (int j = 0; j < 8; ++j) {
            s1[j] += __shfl_xor(s1[j], mask);
            s2[j] += __shfl_xor(s2[j], mask);
        }
    __syncthreads();
    if ((tid & 56) == 0) {
        const int w = tid >> 6;
#pragma unroll
        for (int j = 0; j < 8; ++j) {
            sp[w * 128 + o0 + j]      = s1[j];
            sp[w * 128 + 64 + o0 + j] = s2[j];
        }
    }
    __syncthreads();
    if (tid < 128)
        atomicAdd(&stats[tid], sp[tid] + sp[128 + tid] + sp[256 + tid] + sp[384 + tid]);
}

// ================================================================ hidden conv: TP=128, 4p x 8o + fused stats (in-place)
__global__ __launch_bounds__(256)
void hidden_conv_tile(float* __restrict__ h, const float* __restrict__ W,
                      const float* __restrict__ mr, const float* __restrict__ g,
                      const float* __restrict__ bt, double* __restrict__ stats) {
    __shared__ alignas(16) float smem[128 * 65 + 64 * 68];
    float*  sA  = smem;                               // [128 pix][65]
    float*  sWT = smem + 128 * 65;                    // [64 c][68]
    double* sp  = (double*)smem;                      // aliases sA after compute
    const int tid = threadIdx.x;
    for (int f = tid; f < 4096; f += 256) {
        const int o = f >> 6, c = f & 63;
        sWT[c * 68 + o] = W[f];
    }
    const size_t pix0 = (size_t)blockIdx.x * 128;
    for (int f = tid; f < 8192; f += 256) {
        const int pix = f >> 6, c = f & 63;
        const float hv = h[(pix0 + pix) * 64 + c];
        sA[pix * 65 + c] = bn_lrelu_np(hv, mr[c], mr[64 + c], g[c], bt[c]);
    }
    __syncthreads();

    const int og = tid & 7, pg = tid >> 3;
    const int p0 = pg * 4, o0 = og * 8;
    float acc[4][8];
#pragma unroll
    for (int i = 0; i < 4; ++i)
#pragma unroll
        for (int j = 0; j < 8; ++j) acc[i][j] = 0.f;
#pragma unroll 2
    for (int c = 0; c < 64; ++c) {
        const float4 w0 = *(const float4*)&sWT[c * 68 + o0];
        const float4 w1 = *(const float4*)&sWT[c * 68 + o0 + 4];
        float av[4];
#pragma unroll
        for (int i = 0; i < 4; ++i) av[i] = sA[(p0 + i) * 65 + c];
#pragma unroll
        for (int i = 0; i < 4; ++i) {
            acc[i][0] = __builtin_fmaf(av[i], w0.x, acc[i][0]);
            acc[i][1] = __builtin_fmaf(av[i], w0.y, acc[i][1]);
            acc[i][2] = __builtin_fmaf(av[i], w0.z, acc[i][2]);
            acc[i][3] = __builtin_fmaf(av[i], w0.w, acc[i][3]);
            acc[i][4] = __builtin_fmaf(av[i], w1.x, acc[i][4]);
            acc[i][5] = __builtin_fmaf(av[i], w1.y, acc[i][5]);
            acc[i][6] = __builtin_fmaf(av[i], w1.z, acc[i][6]);
            acc[i][7] = __builtin_fmaf(av[i], w1.w, acc[i][7]);
        }
    }
#pragma unroll
    for (int i = 0; i < 4; ++i) {
        float* dst = &h[(pix0 + p0 + i) * 64 + o0];
        *(float4*)dst       = make_float4(acc[i][0], acc[i][1], acc[i][2], acc[i][3]);
        *(float4*)(dst + 4) = make_float4(acc[i][4], acc[i][5], acc[i][6], acc[i][7]);
    }
    double s1[8], s2[8];
#pragma unroll
    for (int j = 0; j < 8; ++j) { s1[j] = 0.0; s2[j] = 0.0; }
#pragma unroll
    for (int i = 0; i < 4; ++i)
#pragma unroll
        for (int j = 0; j < 8; ++j) {
            const double d = (double)acc[i][j];
            s1[j] += d; s2[j] += d * d;
        }
#pragma unroll
    for (int mask = 8; mask <= 32; mask <<= 1)
#pragma unroll
        for (int j = 0; j < 8; ++j) {
            s1[j] += __shfl_xor(s1[j], mask);
            s2[j] += __shfl_xor(s2[j], mask);
        }
    __syncthreads();
    if ((tid & 56) == 0) {
        const int w = tid >> 6;
#pragma unroll
        for (int j = 0; j < 8; ++j) {
            sp[w * 128 + o0 + j]      = s1[j];
            sp[w * 128 + 64 + o0 + j] = s2[j];
        }
    }
    __syncthreads();
    if (tid < 128)
        atomicAdd(&stats[tid], sp[tid] + sp[128 + tid] + sp[256 + tid] + sp[384 + tid]);
}

// ---------------------------------------------------------------- max over k (BN apply)
__global__ __launch_bounds__(256)
void maxk_np(const float* __restrict__ h, const float* __restrict__ mr,
             const float* __restrict__ g, const float* __restrict__ bt,
             float* __restrict__ out) {
    const int i  = blockIdx.x * 256 + threadIdx.x;
    const int o  = i & 63;
    const int bn = i >> 6;
    const float m = mr[o], r = mr[64 + o], gg = g[o], bb = bt[o];
    const float* hp = h + (size_t)bn * Kc * 64 + o;
    float mx = NEGINF;
#pragma unroll
    for (int k = 0; k < Kc; ++k) mx = fmaxf(mx, bn_lrelu_np(hp[k * 64], m, r, gg, bb));
    out[i] = mx;
}

// ---------------------------------------------------------------- finalize (fp64 stats -> fp32 m,r)
__global__ void finalize_f(const double* __restrict__ stats, float* __restrict__ mr) {
    const int o = threadIdx.x;
    const double inv  = 1.0 / (double)PIXc;
    const double mean = stats[o] * inv;
    const double var  = stats[64 + o] * inv - mean * mean;
    mr[o]      = (float)mean;
    mr[64 + o] = (float)(1.0 / sqrt(var + EPSD));
}

} // namespace

extern "C" void kernel_launch(void* const* d_in, const int* in_sizes, int n_in,
                              void* d_out, int out_size, void* d_ws, size_t ws_size,
                              hipStream_t stream) {
    (void)in_sizes; (void)n_in; (void)out_size; (void)ws_size;
    const float* x     = (const float*)d_in[0];
    const float* w[9]  = {(const float*)d_in[1], (const float*)d_in[2], (const float*)d_in[3],
                          (const float*)d_in[4], (const float*)d_in[5], (const float*)d_in[6],
                          (const float*)d_in[7], (const float*)d_in[8], (const float*)d_in[9]};
    const float* gamma = (const float*)d_in[10];
    const float* beta  = (const float*)d_in[11];
    float* out = (float*)d_out;

    double* statsD = (double*)d_ws;                   // 9*128 doubles
    float*  mr     = (float*)(statsD + 9 * 128);      // 9*128 floats
    float*  xxf    = mr + 9 * 128;                    // BN
    int*  knnIdx   = (int*)(xxf + BNc);               // PIX ints
    float* x1      = (float*)(knnIdx + PIXc);         // BN*64
    float* x2      = x1 + (size_t)BNc * 64;           // BN*64
    float* h       = x2 + (size_t)BNc * 64;           // PIX*64 f = 83.9 MB
    float* S       = h;                               // alias (h dead at kNN time)

    hipMemsetAsync(statsD, 0, 9 * 128 * sizeof(double), stream);

    // ---- stage 1 (C=3)
    compute_xx_xla<3><<<64, 256, 0, stream>>>(x, xxf);
    for (int b = 0; b < Bc; ++b) {
        pair_tile<3><<<4096, 256, 0, stream>>>(x, xxf, S, b);
        brute_select<<<1024, 256, 0, stream>>>(S, knnIdx, b);
    }
    edge_conv3<<<PIXc / 64, 256, 0, stream>>>(x, knnIdx, w[0], h, statsD + 0 * 128);
    finalize_f<<<1, 64, 0, stream>>>(statsD + 0 * 128, mr + 0 * 128);
    hidden_conv_tile<<<PIXc / 128, 256, 0, stream>>>(h, w[1], mr + 0 * 128, gamma + 0 * 64, beta + 0 * 64, statsD + 1 * 128);
    finalize_f<<<1, 64, 0, stream>>>(statsD + 1 * 128, mr + 1 * 128);
    hidden_conv_tile<<<PIXc / 128, 256, 0, stream>>>(h, w[2], mr + 1 * 128, gamma + 1 * 64, beta + 1 * 64, statsD + 2 * 128);
    finalize_f<<<1, 64, 0, stream>>>(statsD + 2 * 128, mr + 2 * 128);
    maxk_np<<<4096, 256, 0, stream>>>(h, mr + 2 * 128, gamma + 2 * 64, beta + 2 * 64, x1);

    // ---- stage 2 (C=64)
    compute_xx_xla<64><<<64, 256, 0, stream>>>(x1, xxf);
    for (int b = 0; b < Bc; ++b) {
        pair_tile<64><<<4096, 256, 0, stream>>>(x1, xxf, S, b);
        brute_select<<<1024, 256, 0, stream>>>(S, knnIdx, b);
    }
    edge_conv64<<<PIXc / 64, 256, 0, stream>>>(x1, knnIdx, w[3], h, statsD + 3 * 128);
    finalize_f<<<1, 64, 0, stream>>>(statsD + 3 * 128, mr + 3 * 128);
    hidden_conv_tile<<<PIXc / 128, 256, 0, stream>>>(h, w[4], mr + 3 * 128, gamma + 3 * 64, beta + 3 * 64, statsD + 4 * 128);
    finalize_f<<<1, 64, 0, stream>>>(statsD + 4 * 128, mr + 4 * 128);
    hidden_conv_tile<<<PIXc / 128, 256, 0, stream>>>(h, w[5], mr + 4 * 128, gamma + 4 * 64, beta + 4 * 64, statsD + 5 * 128);
    finalize_f<<<1, 64, 0, stream>>>(statsD + 5 * 128, mr + 5 * 128);
    maxk_np<<<4096, 256, 0, stream>>>(h, mr + 5 * 128, gamma + 5 * 64, beta + 5 * 64, x2);

    // ---- stage 3 (C=64)
    compute_xx_xla<64><<<64, 256, 0, stream>>>(x2, xxf);
    for (int b = 0; b < Bc; ++b) {
        pair_tile<64><<<4096, 256, 0, stream>>>(x2, xxf, S, b);
        brute_select<<<1024, 256, 0, stream>>>(S, knnIdx, b);
    }
    edge_conv64<<<PIXc / 64, 256, 0, stream>>>(x2, knnIdx, w[6], h, statsD + 6 * 128);
    finalize_f<<<1, 64, 0, stream>>>(statsD + 6 * 128, mr + 6 * 128);
    hidden_conv_tile<<<PIXc / 128, 256, 0, stream>>>(h, w[7], mr + 6 * 128, gamma + 6 * 64, beta + 6 * 64, statsD + 7 * 128);
    finalize_f<<<1, 64, 0, stream>>>(statsD + 7 * 128, mr + 7 * 128);
    hidden_conv_tile<<<PIXc / 128, 256, 0, stream>>>(h, w[8], mr + 7 * 128, gamma + 7 * 64, beta + 7 * 64, statsD + 8 * 128);
    finalize_f<<<1, 64, 0, stream>>>(statsD + 8 * 128, mr + 8 * 128);
    maxk_np<<<4096, 256, 0, stream>>>(h, mr + 8 * 128, gamma + 8 * 64, beta + 8 * 64, out);
}